// Round 5
// baseline (444.510 us; speedup 1.0000x reference)
//
#include <hip/hip_runtime.h>
#include <math.h>

#define H_DIM 1024
#define W_DIM 1536
#define HW_PIX (H_DIM * W_DIM)          // 1572864 pixels per (batch,channel)
#define NBATCH 8
#define QPB (HW_PIX / 4)                // quads per batch = 393216
#define APB 192                          // pass-A blocks per batch
#define CPB 192                          // pass-B (corr) blocks per batch
#define AITERS (QPB / (APB * 256))       // = 8
#define CITERS (QPB / (CPB * 256))       // = 8
#define FBPB (QPB / 256)                 // final blocks per batch = 1536
#define RESOLUTION 1024
#define TC_LEN 256
#define NBINS 4096
#define BPT (NBINS / 256)                // bins per thread in est_kernel = 16

// region constants: 0=highlights 1=shadows 2=whites 3=blacks
#define P0 0.7f
#define P1 0.3f
#define P2 0.9f
#define P3 0.1f
#define IW0 10.0f
#define IW1 (1.0f / 0.12f)
#define IW2 12.5f
#define IW3 12.5f

struct Sliders {
    const float* temperature; const float* tint; const float* exposure; const float* contrast;
    const float* highlights;  const float* shadows; const float* whites; const float* blacks;
    const float* vibrance;    const float* saturation;
};

__device__ __forceinline__ float denorm(float v, float lo, float hi) {
    return lo + 0.5f * (v + 1.0f) * (hi - lo);
}
__device__ __forceinline__ float clamp01(float x) {
    return __builtin_amdgcn_fmed3f(x, 0.f, 1.f);
}
__device__ __forceinline__ float clampf(float x, float lo, float hi) {
    return fminf(fmaxf(x, lo), hi);
}
__device__ __forceinline__ float sigmoidf(float x) {
    float t = __builtin_amdgcn_exp2f(x * -1.4426950408889634f);
    return __builtin_amdgcn_rcpf(1.0f + t);
}

struct FrontP { float sr, sg, sb, em, cf; };

__device__ __forceinline__ FrontP front_params(const Sliders& S, int b) {
    float temp = clampf(denorm(S.temperature[b], 2000.f, 50000.f), 2000.f, 50000.f);
    float tr   = 6500.f / temp;
    float red  = sqrtf(tr);
    float blue = 1.0f / sqrtf(tr);
    float ts   = clampf(denorm(S.tint[b], -150.f, 150.f) * (1.0f / 150.0f), -1.5f, 1.5f);
    float green = 1.0f - 0.1f * ts;
    red  *= (1.0f + 0.05f * ts);
    blue *= (1.0f - 0.05f * ts);
    float norm = fmaxf(fmaxf(red, green), blue);
    float inv  = 1.0f / fmaxf(norm, 1e-4f);
    FrontP p;
    p.sr = red * inv; p.sg = green * inv; p.sb = blue * inv;
    p.em = exp2f(denorm(S.exposure[b], -5.f, 5.f));
    p.cf = 1.0f + denorm(S.contrast[b], -100.f, 100.f) * 0.01f;
    return p;
}

__device__ __forceinline__ float front_chan(float x, float s, float em, float cf) {
    x = clamp01(x);
    x = x * s;
    x = fminf(x * em, 4.0f);
    return clamp01((x - 0.5f) * cf + 0.5f);
}

__device__ __forceinline__ float luminance(float r, float g, float b) {
    return 0.2126f * r + 0.7152f * g + 0.0722f * b;
}

// Block (256 thr) double sum; result on thread 0. Trailing sync -> safely reusable.
__device__ __forceinline__ double block_sum_d(double v) {
    #pragma unroll
    for (int o = 32; o > 0; o >>= 1) v += __shfl_down(v, o, 64);
    __shared__ double s[4];
    int lane = threadIdx.x & 63, wid = threadIdx.x >> 6;
    if (lane == 0) s[wid] = v;
    __syncthreads();
    double r = 0.0;
    if (threadIdx.x == 0) r = s[0] + s[1] + s[2] + s[3];
    __syncthreads();
    return r;
}

// ---------------------------------------------------------------------------
// Pass A: luma0 cache + exact m0 partials + per-batch 4096-bin (count,sum) hist.
template <bool USE_LUMA>
__global__ __launch_bounds__(256)
void hist_kernel(const float* __restrict__ image, Sliders S,
                 float* __restrict__ ws_luma, float* __restrict__ ws_hist,
                 double* __restrict__ ws_m0part) {
    const int b   = blockIdx.x / APB;
    const int blk = blockIdx.x % APB;

    __shared__ float hcnt[NBINS];
    __shared__ float hsum[NBINS];
    for (int j = threadIdx.x; j < NBINS; j += 256) { hcnt[j] = 0.f; hsum[j] = 0.f; }
    __syncthreads();

    FrontP p = front_params(S, b);
    const float LO = 1.0f / (float)NBINS;
    const float HI = (float)(NBINS - 1) / (float)NBINS;
    float cbot = 0.f, sbot = 0.f, ctop = 0.f, stop = 0.f;
    double s0sum = 0.0;

    for (int it = 0; it < AITERS; ++it) {
        const int q   = blk * (256 * AITERS) + it * 256 + threadIdx.x;
        const int off = q * 4;
        const float* base = image + (size_t)b * 3 * HW_PIX + off;
        float4 r4 = *reinterpret_cast<const float4*>(base);
        float4 g4 = *reinterpret_cast<const float4*>(base + HW_PIX);
        float4 b4 = *reinterpret_cast<const float4*>(base + 2 * HW_PIX);
        const float* rr = reinterpret_cast<const float*>(&r4);
        const float* gg = reinterpret_cast<const float*>(&g4);
        const float* bb = reinterpret_cast<const float*>(&b4);
        float4 L;
        float* ll = reinterpret_cast<float*>(&L);
        #pragma unroll
        for (int i = 0; i < 4; i++) {
            float r  = front_chan(rr[i], p.sr, p.em, p.cf);
            float g  = front_chan(gg[i], p.sg, p.em, p.cf);
            float bl = front_chan(bb[i], p.sb, p.em, p.cf);
            float l  = clamp01(luminance(r, g, bl));
            ll[i] = l;
            s0sum += (double)sigmoidf((l - P0) * IW0);
            if (l < LO)       { cbot += 1.f; sbot += l; }
            else if (l >= HI) { ctop += 1.f; stop += l; }
            else {
                int bin = (int)(l * (float)NBINS);   // 1..NBINS-2
                atomicAdd(&hcnt[bin], 1.f);
                atomicAdd(&hsum[bin], l);
            }
        }
        if (USE_LUMA)
            *reinterpret_cast<float4*>(ws_luma + (size_t)b * HW_PIX + off) = L;
    }
    atomicAdd(&hcnt[0], cbot);         atomicAdd(&hsum[0], sbot);
    atomicAdd(&hcnt[NBINS - 1], ctop); atomicAdd(&hsum[NBINS - 1], stop);

    double tot = block_sum_d(s0sum);
    if (threadIdx.x == 0) ws_m0part[b * APB + blk] = tot;
    __syncthreads();

    float* gdst = ws_hist + (size_t)b * 2 * NBINS;
    for (int j = threadIdx.x; j < NBINS; j += 256) {
        float c = hcnt[j];
        if (c != 0.f) {
            atomicAdd(&gdst[j], c);
            atomicAdd(&gdst[NBINS + j], hsum[j]);
        }
    }
}

// ---------------------------------------------------------------------------
// est_kernel: finalize exact m0; push hist reps through chain -> m1e, m2e.
__global__ __launch_bounds__(256)
void est_kernel(const float* __restrict__ ws_hist, const double* __restrict__ ws_m0part,
                Sliders S, float* __restrict__ ws_means, float* __restrict__ ws_est) {
    const int b   = blockIdx.x;
    const int tid = threadIdx.x;
    __shared__ float sbc;

    if (tid == 0) {
        double s = 0.0;
        for (int j = 0; j < APB; ++j) s += ws_m0part[b * APB + j];
        sbc = (float)(s * (1.0 / (double)HW_PIX));
    }
    __syncthreads();
    const float m0 = sbc;
    if (tid == 0) ws_means[b * 4 + 0] = m0;
    __syncthreads();

    float s0 = denorm(S.highlights[b], -100.f, 100.f) * 0.01f;
    float s1 = denorm(S.shadows[b],    -100.f, 100.f) * 0.01f;

    float c[BPT], l[BPT];
    #pragma unroll
    for (int t = 0; t < BPT; ++t) {
        int bin = tid + t * 256;
        c[t] = ws_hist[(size_t)b * 2 * NBINS + bin];
        float s = ws_hist[(size_t)b * 2 * NBINS + NBINS + bin];
        l[t] = (c[t] > 0.f) ? s / c[t] : 0.f;
    }

    // region 0 with exact m0
    #pragma unroll
    for (int t = 0; t < BPT; ++t) {
        float mask = sigmoidf((l[t] - P0) * IW0);
        l[t] = clamp01(l[t] + s0 * (mask - m0));
    }
    // region 1 estimate
    {
        float mask[BPT]; double part = 0.0;
        #pragma unroll
        for (int t = 0; t < BPT; ++t) {
            mask[t] = sigmoidf((l[t] - P1) * IW1);
            part += (double)(c[t] * mask[t]);
        }
        double tot = block_sum_d(part);
        if (tid == 0) sbc = (float)(tot * (1.0 / (double)HW_PIX));
        __syncthreads();
        float m1e = sbc;
        if (tid == 0) ws_est[b * 4 + 1] = m1e;
        #pragma unroll
        for (int t = 0; t < BPT; ++t)
            l[t] = clamp01(l[t] + s1 * (mask[t] - m1e));
        __syncthreads();
    }
    // region 2 estimate
    {
        double part = 0.0;
        #pragma unroll
        for (int t = 0; t < BPT; ++t)
            part += (double)(c[t] * sigmoidf((l[t] - P2) * IW2));
        double tot = block_sum_d(part);
        if (tid == 0) ws_est[b * 4 + 2] = (float)(tot * (1.0 / (double)HW_PIX));
    }
}

// ---------------------------------------------------------------------------
// Pass B: exact Σσ1, Σσ2, Σσ3 + first-order derivative sums wrt (δm1, δm2).
template <bool USE_LUMA>
__global__ __launch_bounds__(256)
void corr_kernel(const float* __restrict__ image, const float* __restrict__ ws_luma,
                 Sliders S, const float* __restrict__ ws_means,
                 const float* __restrict__ ws_est,
                 double* __restrict__ ws_dsum, float* __restrict__ ws_fsum) {
    const int b   = blockIdx.x / CPB;
    const int blk = blockIdx.x % CPB;

    const float m0  = ws_means[b * 4 + 0];
    const float m1e = ws_est[b * 4 + 1];
    const float m2e = ws_est[b * 4 + 2];
    const float s0 = denorm(S.highlights[b], -100.f, 100.f) * 0.01f;
    const float s1 = denorm(S.shadows[b],    -100.f, 100.f) * 0.01f;
    const float s2 = denorm(S.whites[b],     -100.f, 100.f) * 0.01f;

    FrontP p = front_params(S, b);   // used only if !USE_LUMA

    double a1 = 0.0, a2 = 0.0, a3 = 0.0;
    float d21 = 0.f, d31 = 0.f, d32 = 0.f;

    for (int it = 0; it < CITERS; ++it) {
        const int q   = blk * (256 * CITERS) + it * 256 + threadIdx.x;
        const int off = q * 4;
        float4 L;
        if (USE_LUMA) {
            L = *reinterpret_cast<const float4*>(ws_luma + (size_t)b * HW_PIX + off);
        } else {
            const float* base = image + (size_t)b * 3 * HW_PIX + off;
            float4 r4 = *reinterpret_cast<const float4*>(base);
            float4 g4 = *reinterpret_cast<const float4*>(base + HW_PIX);
            float4 b4 = *reinterpret_cast<const float4*>(base + 2 * HW_PIX);
            const float* rr = reinterpret_cast<const float*>(&r4);
            const float* gg = reinterpret_cast<const float*>(&g4);
            const float* bb = reinterpret_cast<const float*>(&b4);
            float* ll = reinterpret_cast<float*>(&L);
            #pragma unroll
            for (int i = 0; i < 4; i++) {
                float r  = front_chan(rr[i], p.sr, p.em, p.cf);
                float g  = front_chan(gg[i], p.sg, p.em, p.cf);
                float bl = front_chan(bb[i], p.sb, p.em, p.cf);
                ll[i] = clamp01(luminance(r, g, bl));
            }
        }
        const float* ll = reinterpret_cast<const float*>(&L);
        #pragma unroll
        for (int i = 0; i < 4; i++) {
            float l0 = ll[i];
            float g0 = sigmoidf((l0 - P0) * IW0);
            float u1 = l0 + s0 * (g0 - m0);
            float l1 = clamp01(u1);

            float g1 = sigmoidf((l1 - P1) * IW1);
            a1 += (double)g1;

            float u2 = l1 + s1 * (g1 - m1e);
            float l2 = clamp01(u2);
            float ind2 = (u2 > 0.f && u2 < 1.f) ? 1.f : 0.f;
            float g2 = sigmoidf((l2 - P2) * IW2);
            a2 += (double)g2;
            float dl2 = -s1 * ind2;                 // dl2/d(dm1)
            float dg2 = g2 * (1.f - g2) * IW2 * dl2; // dσ2/d(dm1)
            d21 += dg2;

            float u3 = l2 + s2 * (g2 - m2e);
            float l3 = clamp01(u3);
            float ind3 = (u3 > 0.f && u3 < 1.f) ? 1.f : 0.f;
            float g3 = sigmoidf((l3 - P3) * IW3);
            a3 += (double)g3;
            float dl3_1 = ind3 * (dl2 + s2 * dg2);  // dl3/d(dm1)
            float dl3_2 = ind3 * (-s2);             // dl3/d(dm2)
            float sp3 = g3 * (1.f - g3) * IW3;
            d31 += sp3 * dl3_1;
            d32 += sp3 * dl3_2;
        }
    }

    double t1 = block_sum_d(a1);
    double t2 = block_sum_d(a2);
    double t3 = block_sum_d(a3);
    double f1 = block_sum_d((double)d21);
    double f2 = block_sum_d((double)d31);
    double f3 = block_sum_d((double)d32);
    if (threadIdx.x == 0) {
        ws_dsum[(0 * NBATCH + b) * CPB + blk] = t1;
        ws_dsum[(1 * NBATCH + b) * CPB + blk] = t2;
        ws_dsum[(2 * NBATCH + b) * CPB + blk] = t3;
        ws_fsum[(0 * NBATCH + b) * CPB + blk] = (float)f1;
        ws_fsum[(1 * NBATCH + b) * CPB + blk] = (float)f2;
        ws_fsum[(2 * NBATCH + b) * CPB + blk] = (float)f3;
    }
}

// ---------------------------------------------------------------------------
// solve_kernel: first-order-corrected exact means.
__global__ __launch_bounds__(256)
void solve_kernel(const double* __restrict__ ws_dsum, const float* __restrict__ ws_fsum,
                  const float* __restrict__ ws_est, float* __restrict__ ws_means) {
    const int b   = blockIdx.x;
    const int tid = threadIdx.x;
    double v;
    #define RED(dst, expr) v = (tid < CPB) ? (expr) : 0.0; dst = block_sum_d(v);
    double S1, S2, S3, D21, D31, D32;
    RED(S1,  ws_dsum[(0 * NBATCH + b) * CPB + tid]);
    RED(S2,  ws_dsum[(1 * NBATCH + b) * CPB + tid]);
    RED(S3,  ws_dsum[(2 * NBATCH + b) * CPB + tid]);
    RED(D21, (double)ws_fsum[(0 * NBATCH + b) * CPB + tid]);
    RED(D31, (double)ws_fsum[(1 * NBATCH + b) * CPB + tid]);
    RED(D32, (double)ws_fsum[(2 * NBATCH + b) * CPB + tid]);
    #undef RED
    if (tid == 0) {
        const double invN = 1.0 / (double)HW_PIX;
        double m1 = S1 * invN;
        double d1 = m1 - (double)ws_est[b * 4 + 1];
        double m2 = S2 * invN + (D21 * invN) * d1;
        double d2 = m2 - (double)ws_est[b * 4 + 2];
        double m3 = S3 * invN + (D31 * invN) * d1 + (D32 * invN) * d2;
        ws_means[b * 4 + 1] = (float)m1;
        ws_means[b * 4 + 2] = (float)m2;
        ws_means[b * 4 + 3] = (float)m3;
    }
}

// ---------------------------------------------------------------------------
// Final pass (identical numerics to the R3 passing version).
__global__ __launch_bounds__(256)
void final_kernel(const float* __restrict__ image, const float* __restrict__ tone_curve,
                  Sliders S, const float* __restrict__ ws_means, float* __restrict__ out) {
    const int b = blockIdx.x / FBPB;

    __shared__ float curve[RESOLUTION];
    const float* tc = tone_curve + b * TC_LEN;
    for (int j = threadIdx.x; j < RESOLUTION; j += 256) {
        float src = (float)j * ((float)(TC_LEN - 1) / (float)(RESOLUTION - 1));
        float fi  = floorf(src);
        int   i0  = (int)fi;
        int   i1  = min(i0 + 1, TC_LEN - 1);
        float w   = src - fi;
        curve[j]  = tc[i0] * (1.0f - w) + tc[i1] * w;
    }
    __syncthreads();

    const int q   = (blockIdx.x % FBPB) * 256 + threadIdx.x;
    const int off = q * 4;

    const float pivots[4] = {P0, P1, P2, P3};
    const float invw[4]   = {IW0, IW1, IW2, IW3};
    const float* sliders[4] = {S.highlights, S.shadows, S.whites, S.blacks};

    FrontP p = front_params(S, b);
    float strength[4], meanv[4];
    #pragma unroll
    for (int k = 0; k < 4; k++) {
        strength[k] = denorm(sliders[k][b], -100.f, 100.f) * 0.01f;
        meanv[k]    = ws_means[b * 4 + k];
    }
    float vib  = denorm(S.vibrance[b],   -100.f, 100.f) * 0.01f;
    float satg = 1.0f + denorm(S.saturation[b], -100.f, 100.f) * 0.01f;

    const float* base = image + (size_t)b * 3 * HW_PIX + off;
    float4 r4 = *reinterpret_cast<const float4*>(base);
    float4 g4 = *reinterpret_cast<const float4*>(base + HW_PIX);
    float4 b4 = *reinterpret_cast<const float4*>(base + 2 * HW_PIX);
    float* rr = reinterpret_cast<float*>(&r4);
    float* gg = reinterpret_cast<float*>(&g4);
    float* bb = reinterpret_cast<float*>(&b4);

    #pragma unroll
    for (int i = 0; i < 4; i++) {
        float r  = front_chan(rr[i], p.sr, p.em, p.cf);
        float g  = front_chan(gg[i], p.sg, p.em, p.cf);
        float bl = front_chan(bb[i], p.sb, p.em, p.cf);
        float lum = clamp01(luminance(r, g, bl));

        #pragma unroll
        for (int k = 0; k < 4; k++) {
            float mask = sigmoidf((lum - pivots[k]) * invw[k]);
            float nl   = clamp01(lum + strength[k] * (mask - meanv[k]));
            float ratio = (lum > 1e-4f) ? nl * __builtin_amdgcn_rcpf(lum) : 1.0f;
            r  = fminf(r * ratio, 1.f);
            g  = fminf(g * ratio, 1.f);
            bl = fminf(bl * ratio, 1.f);
            lum = nl;
        }

        float tl = clamp01(luminance(r, g, bl));
        float coords = tl * (float)(RESOLUTION - 1);
        float fidx = floorf(coords);
        int   i0 = (int)fidx;
        int   i1 = min(i0 + 1, RESOLUTION - 1);
        float w  = coords - fidx;
        float target = (1.0f - w) * curve[i0] + w * curve[i1];
        float ratio  = (tl > 1e-5f) ? target * __builtin_amdgcn_rcpf(tl) : 1.0f;
        r  = fminf(r * ratio, 1.f);
        g  = fminf(g * ratio, 1.f);
        bl = fminf(bl * ratio, 1.f);

        float l2 = luminance(r, g, bl);
        float cr = r - l2, cg = g - l2, cb = bl - l2;
        float cn = sqrtf(cr * cr + cg * cg + cb * cb + 1e-6f);
        float gmask = __builtin_amdgcn_exp2f(cn * -5.771f);
        float vg = __builtin_amdgcn_fmed3f(1.0f + vib * gmask, 0.2f, 4.0f);
        r  = clamp01(l2 + cr * vg);
        g  = clamp01(l2 + cg * vg);
        bl = clamp01(l2 + cb * vg);

        float l3 = luminance(r, g, bl);
        r  = clamp01(l3 + (r - l3) * satg);
        g  = clamp01(l3 + (g - l3) * satg);
        bl = clamp01(l3 + (bl - l3) * satg);

        rr[i] = r; gg[i] = g; bb[i] = bl;
    }

    float* obase = out + (size_t)b * 3 * HW_PIX + off;
    *reinterpret_cast<float4*>(obase)              = r4;
    *reinterpret_cast<float4*>(obase + HW_PIX)     = g4;
    *reinterpret_cast<float4*>(obase + 2 * HW_PIX) = b4;
}

extern "C" void kernel_launch(void* const* d_in, const int* in_sizes, int n_in,
                              void* d_out, int out_size, void* d_ws, size_t ws_size,
                              hipStream_t stream) {
    const float* image      = (const float*)d_in[0];
    const float* tone_curve = (const float*)d_in[1];
    Sliders S;
    S.temperature = (const float*)d_in[2];
    S.tint        = (const float*)d_in[3];
    S.exposure    = (const float*)d_in[4];
    S.contrast    = (const float*)d_in[5];
    S.highlights  = (const float*)d_in[6];
    S.shadows     = (const float*)d_in[7];
    S.whites      = (const float*)d_in[8];
    S.blacks      = (const float*)d_in[9];
    S.vibrance    = (const float*)d_in[10];
    S.saturation  = (const float*)d_in[11];
    float* out = (float*)d_out;

    // ws layout (all 256B-aligned):
    char* base = (char*)d_ws;
    size_t off = 0;
    float*  ws_means  = (float*)(base + off);  off += 256;                    // 8x4 floats
    float*  ws_est    = (float*)(base + off);  off += 256;                    // 8x4 floats
    float*  ws_hist   = (float*)(base + off);  off += (size_t)NBATCH * 2 * NBINS * sizeof(float);   // 256 KB
    double* ws_m0part = (double*)(base + off); off += (size_t)NBATCH * APB * sizeof(double);        // 12 KB
    double* ws_dsum   = (double*)(base + off); off += (size_t)3 * NBATCH * CPB * sizeof(double);    // 36 KB
    float*  ws_fsum   = (float*)(base + off);  off += (size_t)3 * NBATCH * CPB * sizeof(float);     // 18 KB
    off = (off + 255) & ~(size_t)255;
    float*  ws_luma   = (float*)(base + off);
    bool use_luma = ws_size >= off + (size_t)NBATCH * HW_PIX * sizeof(float); // +50.3 MB

    hipMemsetAsync(ws_hist, 0, (size_t)NBATCH * 2 * NBINS * sizeof(float), stream);

    dim3 block(256);
    if (use_luma) {
        hist_kernel<true><<<dim3(NBATCH * APB), block, 0, stream>>>(image, S, ws_luma, ws_hist, ws_m0part);
        est_kernel<<<dim3(NBATCH), block, 0, stream>>>(ws_hist, ws_m0part, S, ws_means, ws_est);
        corr_kernel<true><<<dim3(NBATCH * CPB), block, 0, stream>>>(image, ws_luma, S, ws_means, ws_est, ws_dsum, ws_fsum);
    } else {
        hist_kernel<false><<<dim3(NBATCH * APB), block, 0, stream>>>(image, S, ws_luma, ws_hist, ws_m0part);
        est_kernel<<<dim3(NBATCH), block, 0, stream>>>(ws_hist, ws_m0part, S, ws_means, ws_est);
        corr_kernel<false><<<dim3(NBATCH * CPB), block, 0, stream>>>(image, ws_luma, S, ws_means, ws_est, ws_dsum, ws_fsum);
    }
    solve_kernel<<<dim3(NBATCH), block, 0, stream>>>(ws_dsum, ws_fsum, ws_est, ws_means);
    final_kernel<<<dim3(NBATCH * FBPB), block, 0, stream>>>(image, tone_curve, S, ws_means, out);
}